// Round 5
// baseline (10964.382 us; speedup 1.0000x reference)
//
#include <hip/hip_runtime.h>
#include <math.h>

#define EPSF 1e-5f

typedef _Float16 f16;
typedef __attribute__((ext_vector_type(8))) _Float16 f16x8;
typedef __attribute__((ext_vector_type(4))) float f32x4;

// ---------------- basis helpers ----------------
__device__ __forceinline__ void tap_geom(int tap, float hats[4], float xh[3], float& mask) {
  int d = tap / 25, h = (tap / 5) % 5, w = tap % 5;
  float X = (float)(d - 2), Y = (float)(h - 2), Z = (float)(w - 2);
  float r = sqrtf(X * X + Y * Y + Z * Z);
#pragma unroll
  for (int k = 0; k < 4; ++k) hats[k] = fmaxf(1.0f - fabsf(r - (float)k), 0.0f);
  float inv = (r > 0.0f) ? (1.0f / r) : 0.0f;
  xh[0] = X * inv; xh[1] = Y * inv; xh[2] = Z * inv;
  mask = (r > 0.0f) ? 1.0f : 0.0f;
}

// K1 layout: [(i*125 + tap)*VEC*3 + (o*3+j)]  (fp32)
__global__ void build_k1(const float* __restrict__ w1, float* __restrict__ K1,
                         int VEC, int SIN) {
  int OC3 = VEC * 3;
  int total = SIN * 125 * OC3;
  for (int idx = blockIdx.x * blockDim.x + threadIdx.x; idx < total;
       idx += gridDim.x * blockDim.x) {
    int oc = idx % OC3;
    int tap = (idx / OC3) % 125;
    int i = idx / (OC3 * 125);
    int o = oc / 3, j = oc % 3;
    float hats[4], xh[3], mask;
    tap_geom(tap, hats, xh, mask);
    float R = 0.f;
#pragma unroll
    for (int k = 0; k < 4; ++k) R += w1[(o * SIN + i) * 4 + k] * hats[k];
    K1[idx] = xh[j] * R;
  }
}

// ---- fp32 K2 (for fp32 path): [((tap*VEC + cv)*12 + comp)*SOUT + o] ----
__global__ void build_k2(const float* __restrict__ wA, const float* __restrict__ wB,
                         float* __restrict__ K2, int VEC, int SOUT) {
  int total = 125 * VEC * 12 * SOUT;
  for (int idx = blockIdx.x * blockDim.x + threadIdx.x; idx < total;
       idx += gridDim.x * blockDim.x) {
    int o = idx % SOUT;
    int comp = (idx / SOUT) % 12;
    int cv = (idx / (SOUT * 12)) % VEC;
    int tap = idx / (SOUT * 12 * VEC);
    float hats[4], xh[3], mask;
    tap_geom(tap, hats, xh, mask);
    float val;
    if (comp < 3) {
      float RA = 0.f;
#pragma unroll
      for (int k = 0; k < 4; ++k) RA += wA[(o * VEC + cv) * 4 + k] * hats[k];
      val = RA * xh[comp];
    } else {
      int ij = comp - 3;
      int ii = ij / 3, jj = ij % 3;
      float RB[3];
#pragma unroll
      for (int m = 0; m < 3; ++m) {
        float r = 0.f;
#pragma unroll
        for (int k = 0; k < 4; ++k) r += wB[((o * VEC + cv) * 3 + m) * 4 + k] * hats[k];
        RB[m] = r;
      }
      float a0 = (ii == jj) ? 1.0f : 0.0f;
      float a1 = 0.0f;
      if (ii != jj) {
        int l = 3 - ii - jj;
        float sgn = (((jj - ii + 3) % 3) == 1) ? 1.0f : -1.0f;
        a1 = sgn * xh[l];
      }
      float a2 = xh[ii] * xh[jj] - ((ii == jj) ? (mask / 3.0f) : 0.0f);
      val = RB[0] * a0 + RB[1] * a1 + RB[2] * a2;
    }
    K2[idx] = val;
  }
}

// ---- MFMA K2 (f16): [tap][n=16][C_pad] ----
__global__ void build_k2b(const float* __restrict__ wA, const float* __restrict__ wB,
                          f16* __restrict__ K2, int VEC, int SOUT, int CP) {
  int total = 125 * 16 * CP;
  for (int idx = blockIdx.x * blockDim.x + threadIdx.x; idx < total;
       idx += gridDim.x * blockDim.x) {
    int c = idx % CP;
    int n = (idx / CP) % 16;
    int tap = idx / (CP * 16);
    float val = 0.f;
    if (n < SOUT && c < VEC * 12) {
      float hats[4], xh[3], mask;
      tap_geom(tap, hats, xh, mask);
      if (c < VEC * 3) {
        int cv = c / 3, j = c % 3;
        float RA = 0.f;
#pragma unroll
        for (int k = 0; k < 4; ++k) RA += wA[(n * VEC + cv) * 4 + k] * hats[k];
        val = RA * xh[j];
      } else {
        int q = c - VEC * 3;
        int cv = q / 9, ij = q % 9;
        int ii = ij / 3, jj = ij % 3;
        float RB[3];
#pragma unroll
        for (int m = 0; m < 3; ++m) {
          float r = 0.f;
#pragma unroll
          for (int k = 0; k < 4; ++k) r += wB[((n * VEC + cv) * 3 + m) * 4 + k] * hats[k];
          RB[m] = r;
        }
        float a0 = (ii == jj) ? 1.0f : 0.0f;
        float a1 = 0.0f;
        if (ii != jj) {
          int l = 3 - ii - jj;
          float sgn = (((jj - ii + 3) % 3) == 1) ? 1.0f : -1.0f;
          a1 = sgn * xh[l];
        }
        float a2 = xh[ii] * xh[jj] - ((ii == jj) ? (mask / 3.0f) : 0.0f);
        val = RB[0] * a0 + RB[1] * a1 + RB[2] * a2;
      }
    }
    K2[idx] = (f16)val;
  }
}

// ---------------- fp32 conv1 (V layout [b][oc][pos]) ----------------
template <int SIN, int VEC>
__global__ __launch_bounds__(256) void conv1_k(const float* __restrict__ s,
                                               const float* __restrict__ K1,
                                               float* __restrict__ v, int B, int IS, int OS) {
  constexpr int OC3 = VEC * 3;
  int iss = IS * IS * IS;
  int oss = OS * OS * OS;
  int total = B * oss;
  for (int idx = blockIdx.x * blockDim.x + threadIdx.x; idx < total;
       idx += gridDim.x * blockDim.x) {
    int x = idx % OS;
    int y = (idx / OS) % OS;
    int z = (idx / (OS * OS)) % OS;
    int b = idx / oss;
    float acc[OC3];
#pragma unroll
    for (int o = 0; o < OC3; ++o) acc[o] = 0.f;
    for (int i = 0; i < SIN; ++i) {
      const float* sb = s + ((long)b * SIN + i) * iss;
      for (int d = 0; d < 5; ++d) {
        int iz = 2 * z - 3 + d;
        if ((unsigned)iz >= (unsigned)IS) continue;
        for (int h = 0; h < 5; ++h) {
          int iy = 2 * y - 3 + h;
          if ((unsigned)iy >= (unsigned)IS) continue;
#pragma unroll
          for (int w = 0; w < 5; ++w) {
            int ix = 2 * x - 3 + w;
            if ((unsigned)ix >= (unsigned)IS) continue;
            float sv = sb[(iz * IS + iy) * IS + ix];
            const float* kp = K1 + (i * 125 + (d * 25 + h * 5 + w)) * OC3;
#pragma unroll
            for (int o = 0; o < OC3; ++o) acc[o] = fmaf(sv, kp[o], acc[o]);
          }
        }
      }
    }
    int p = (z * OS + y) * OS + x;
#pragma unroll
    for (int oc = 0; oc < OC3; ++oc) v[((long)b * OC3 + oc) * oss + p] = acc[oc];
  }
}

// ---------------- fp32 conv2 (t on the fly) ----------------
template <int VEC, int SOUT>
__global__ __launch_bounds__(256) void conv2_k(const float* __restrict__ v,
                                               const float* __restrict__ K2,
                                               float* __restrict__ out, int B, int IS, int OS) {
  int iss = IS * IS * IS;
  int oss = OS * OS * OS;
  int total = B * oss;
  for (int idx = blockIdx.x * blockDim.x + threadIdx.x; idx < total;
       idx += gridDim.x * blockDim.x) {
    int x = idx % OS;
    int y = (idx / OS) % OS;
    int z = (idx / (OS * OS)) % OS;
    int b = idx / oss;
    float acc[SOUT];
#pragma unroll
    for (int o = 0; o < SOUT; ++o) acc[o] = 0.f;
    for (int d = 0; d < 5; ++d) {
      int iz = z - 3 + d;
      if ((unsigned)iz >= (unsigned)IS) continue;
      for (int h = 0; h < 5; ++h) {
        int iy = y - 3 + h;
        if ((unsigned)iy >= (unsigned)IS) continue;
        for (int w = 0; w < 5; ++w) {
          int ix = x - 3 + w;
          if ((unsigned)ix >= (unsigned)IS) continue;
          int tap = d * 25 + h * 5 + w;
          int ppos = (iz * IS + iy) * IS + ix;
          const float* kt = K2 + (long)tap * (VEC * 12 * SOUT);
          const float* vb = v + ((long)b * VEC * 3) * iss + ppos;
#pragma unroll 1
          for (int cv = 0; cv < VEC; ++cv) {
            float v0 = vb[(cv * 3 + 0) * iss];
            float v1 = vb[(cv * 3 + 1) * iss];
            float v2 = vb[(cv * 3 + 2) * iss];
            const float* kp = kt + cv * (12 * SOUT);
            float vals[12] = {v0, v1, v2,
                              v0 * v0, v0 * v1, v0 * v2,
                              v1 * v0, v1 * v1, v1 * v2,
                              v2 * v0, v2 * v1, v2 * v2};
#pragma unroll
            for (int comp = 0; comp < 12; ++comp) {
              float vv = vals[comp];
#pragma unroll
              for (int o = 0; o < SOUT; ++o)
                acc[o] = fmaf(vv, kp[comp * SOUT + o], acc[o]);
            }
          }
        }
      }
    }
    int p = (z * OS + y) * OS + x;
#pragma unroll
    for (int o = 0; o < SOUT; ++o) out[((long)b * SOUT + o) * oss + p] = acc[o];
  }
}

// ---------------- MFMA conv1: fp32 conv fused with f16 vt build ----------------
// VT[b][z][y][cg][x][8]; channels c=cg*8+e: c<OC3: v; OC3<=c<VEC*12: t; else 0.
template <int SIN, int VEC, int CP8>
__global__ __launch_bounds__(256) void conv1_vt(const float* __restrict__ s,
                                                const float* __restrict__ K1,
                                                f16* __restrict__ VT,
                                                int Bc, int IS, int OS) {
  constexpr int OC3 = VEC * 3;
  int iss = IS * IS * IS;
  int oss = OS * OS * OS;
  int total = Bc * oss;
  for (int idx = blockIdx.x * blockDim.x + threadIdx.x; idx < total;
       idx += gridDim.x * blockDim.x) {
    int x = idx % OS;
    int y = (idx / OS) % OS;
    int z = (idx / (OS * OS)) % OS;
    int b = idx / oss;
    float acc[OC3];
#pragma unroll
    for (int o = 0; o < OC3; ++o) acc[o] = 0.f;
    for (int i = 0; i < SIN; ++i) {
      const float* sb = s + ((long)b * SIN + i) * iss;
      for (int d = 0; d < 5; ++d) {
        int iz = 2 * z - 3 + d;
        if ((unsigned)iz >= (unsigned)IS) continue;
        for (int h = 0; h < 5; ++h) {
          int iy = 2 * y - 3 + h;
          if ((unsigned)iy >= (unsigned)IS) continue;
#pragma unroll
          for (int w = 0; w < 5; ++w) {
            int ix = 2 * x - 3 + w;
            if ((unsigned)ix >= (unsigned)IS) continue;
            float sv = sb[(iz * IS + iy) * IS + ix];
            const float* kp = K1 + (i * 125 + (d * 25 + h * 5 + w)) * OC3;
#pragma unroll
            for (int o = 0; o < OC3; ++o) acc[o] = fmaf(sv, kp[o], acc[o]);
          }
        }
      }
    }
    long rowbase = (((long)(b * OS + z) * OS + y) * CP8) * (long)OS * 8 + (long)x * 8;
#pragma unroll
    for (int cg = 0; cg < CP8; ++cg) {
      f16x8 pack;
#pragma unroll
      for (int e = 0; e < 8; ++e) {
        int c = cg * 8 + e;
        float v;
        if (c < OC3) v = acc[c];
        else if (c < VEC * 12) {
          int q = c - OC3;
          int cv = q / 9, r9 = q % 9;
          v = acc[cv * 3 + r9 / 3] * acc[cv * 3 + r9 % 3];
        } else v = 0.f;
        pack[e] = (f16)v;
      }
      *(f16x8*)(VT + rowbase + (long)cg * OS * 8) = pack;
    }
  }
}

// ---------------- MFMA conv2: one wave = 16 x-positions x 16 out channels ------
template <int CP8, int SOUT>
__global__ __launch_bounds__(256) void conv2_mfma(const f16* __restrict__ VT,
                                                  const f16* __restrict__ K2,
                                                  float* __restrict__ out,
                                                  int Bc, int IS, int OS, int XG) {
  constexpr int KS = CP8 / 4;
  constexpr int CP = CP8 * 8;
  int wid = (int)((blockIdx.x * (long)blockDim.x + threadIdx.x) >> 6);
  int lane = threadIdx.x & 63;
  int total = Bc * OS * OS * XG;
  if (wid >= total) return;
  int xg = wid % XG;
  int y = (wid / XG) % OS;
  int z = (wid / (XG * OS)) % OS;
  int b = wid / (XG * OS * OS);
  int x0 = xg * 16;
  int lm = lane & 15;
  int g = lane >> 4;
  int xr = x0 + lm;

  f32x4 acc = {0.f, 0.f, 0.f, 0.f};
  const f16* bp = K2 + (long)lm * CP;

  for (int d = 0; d < 5; ++d) {
    int zi = z - 3 + d;
    if ((unsigned)zi >= (unsigned)IS) continue;
    for (int h = 0; h < 5; ++h) {
      int yi = y - 3 + h;
      if ((unsigned)yi >= (unsigned)IS) continue;
      const f16* ap = VT + (((long)(b * IS + zi) * IS + yi) * CP8) * (long)IS * 8;
      int tb = (d * 25 + h * 5) * 16 * CP;
#pragma unroll
      for (int w = 0; w < 5; ++w) {
        int xi = xr - 3 + w;
        bool xok = (unsigned)xi < (unsigned)IS;
        int tapoff = tb + w * 16 * CP;
#pragma unroll
        for (int ks = 0; ks < KS; ++ks) {
          f16x8 af = {};
          if (xok) af = *(const f16x8*)(ap + ((long)(ks * 4 + g) * IS + xi) * 8);
          f16x8 bf_ = *(const f16x8*)(bp + tapoff + (ks * 4 + g) * 8);
          acc = __builtin_amdgcn_mfma_f32_16x16x32_f16(af, bf_, acc, 0, 0, 0);
        }
      }
    }
  }
  if (lm < SOUT) {
    int oss = OS * OS * OS;
    float* op = out + ((long)b * SOUT + lm) * oss + (z * OS + y) * OS;
#pragma unroll
    for (int r = 0; r < 4; ++r) {
      int xm = x0 + g * 4 + r;
      if (xm < OS) op[xm] = acc[r];
    }
  }
}

// ---------------- batch-norm reductions (two-stage, deterministic) ----------------
__global__ void stats1(const float* __restrict__ a, float* __restrict__ part,
                       int B, int C, int ss, int nblk) {
  int c = blockIdx.y;
  int tid = threadIdx.x;
  float s = 0.f, s2 = 0.f;
  for (int b = 0; b < B; ++b) {
    const float* ab = a + ((long)b * C + c) * ss;
    for (int p = blockIdx.x * blockDim.x + tid; p < ss; p += nblk * blockDim.x) {
      float x = ab[p];
      s += x;
      s2 += x * x;
    }
  }
  __shared__ float sh[256], sh2[256];
  sh[tid] = s; sh2[tid] = s2;
  __syncthreads();
  for (int off = 128; off > 0; off >>= 1) {
    if (tid < off) { sh[tid] += sh[tid + off]; sh2[tid] += sh2[tid + off]; }
    __syncthreads();
  }
  if (tid == 0) {
    part[(c * nblk + blockIdx.x) * 2 + 0] = sh[0];
    part[(c * nblk + blockIdx.x) * 2 + 1] = sh2[0];
  }
}

__global__ void stats2(const float* __restrict__ part, float* __restrict__ stats,
                       int nblk, float invn) {
  int c = blockIdx.x;
  int tid = threadIdx.x;
  float s = 0.f, s2 = 0.f;
  for (int i = tid; i < nblk; i += blockDim.x) {
    s += part[(c * nblk + i) * 2 + 0];
    s2 += part[(c * nblk + i) * 2 + 1];
  }
  __shared__ float sh[256], sh2[256];
  sh[tid] = s; sh2[tid] = s2;
  __syncthreads();
  for (int off = 128; off > 0; off >>= 1) {
    if (tid < off) { sh[tid] += sh[tid + off]; sh2[tid] += sh2[tid + off]; }
    __syncthreads();
  }
  if (tid == 0) {
    float m = sh[0] * invn;
    float var = sh2[0] * invn - m * m;
    stats[c * 2 + 0] = m;
    stats[c * 2 + 1] = 1.0f / sqrtf(var + EPSF);
  }
}

__global__ void bn_apply(const float* __restrict__ in, float* __restrict__ out,
                         const float* __restrict__ stats, const float* __restrict__ g,
                         const float* __restrict__ be, const float* __restrict__ bias,
                         int C, int ss, int relu) {
  int bc = blockIdx.y;
  int c = bc % C;
  float m = stats[c * 2 + 0];
  float r = stats[c * 2 + 1];
  float ga = g ? g[c] : 1.f;
  float bb = be ? be[c] : 0.f;
  float bi = bias ? bias[c] : 0.f;
  const float* ip = in + (long)bc * ss;
  float* op = out + (long)bc * ss;
  for (int p = blockIdx.x * blockDim.x + threadIdx.x; p < ss; p += gridDim.x * blockDim.x) {
    float xn = (ip[p] - m) * r * ga + bb;
    if (relu) xn = fmaxf(xn + bi, 0.f);
    op[p] = xn;
  }
}

// ---------------- pooling + final batch-norm ----------------
__global__ void pool_k(const float* __restrict__ in, float* __restrict__ pooled, int ss) {
  int bc = blockIdx.x;
  int tid = threadIdx.x;
  const float* p = in + (long)bc * ss;
  float s = 0.f;
  for (int e = tid; e < ss; e += blockDim.x) s += p[e];
  __shared__ float sh[256];
  sh[tid] = s;
  __syncthreads();
  for (int off = 128; off > 0; off >>= 1) {
    if (tid < off) sh[tid] += sh[tid + off];
    __syncthreads();
  }
  if (tid == 0) pooled[bc] = sh[0] / (float)ss;
}

__global__ void final_bn(const float* __restrict__ pooled, const float* __restrict__ g,
                         const float* __restrict__ be, float* __restrict__ out,
                         int B, int C) {
  int tid = threadIdx.x;
  __shared__ float mv[16][2];
  if (tid < C) {
    float s = 0.f, s2 = 0.f;
    for (int b = 0; b < B; ++b) {
      float x = pooled[b * C + tid];
      s += x;
      s2 += x * x;
    }
    float m = s / (float)B;
    float var = s2 / (float)B - m * m;
    mv[tid][0] = m;
    mv[tid][1] = 1.0f / sqrtf(var + EPSF);
  }
  __syncthreads();
  for (int i = tid; i < B * C; i += blockDim.x) {
    int c = i % C;
    out[i] = g[c] * (pooled[i] - mv[c][0]) * mv[c][1] + be[c];
  }
}

// ---------------- host ----------------
extern "C" void kernel_launch(void* const* d_in, const int* in_sizes, int n_in,
                              void* d_out, int out_size, void* d_ws, size_t ws_size,
                              hipStream_t stream) {
  (void)in_sizes; (void)n_in; (void)out_size; (void)ws_size;
  const float* x = (const float*)d_in[0];
  const float* w1[5]; const float* wA[5]; const float* wB[5];
  const float* bias[5]; const float* gam[5]; const float* bet[5];
  for (int i = 0; i < 5; ++i) {
    w1[i]  = (const float*)d_in[1 + i * 6 + 0];
    wA[i]  = (const float*)d_in[1 + i * 6 + 1];
    wB[i]  = (const float*)d_in[1 + i * 6 + 2];
    bias[i]= (const float*)d_in[1 + i * 6 + 3];
    gam[i] = (const float*)d_in[1 + i * 6 + 4];
    bet[i] = (const float*)d_in[1 + i * 6 + 5];
  }
  const float* gamma_out = (const float*)d_in[31];
  const float* beta_out  = (const float*)d_in[32];
  float* out = (float*)d_out;

  // workspace carve — identical to round-4 (proven fit ~135 MB)
  float* A     = (float*)d_ws;            // 8,388,608
  float* Bb    = A + 8388608;             // 10,976,000
  float* V     = Bb + 10976000;           // 13,799,808 floats (fp32 V / f16 VT = 27.6M f16)
  float* K1    = V + 13799808;            // 96,000
  float* K2    = K1 + 96000;              // 384,000 floats (fp32 K2 / f16 K2h)
  float* part  = K2 + 384000;             // 8,192
  float* stats = part + 16 * 256 * 2;
  float* pooled= stats + 64;
  f16* VT  = (f16*)V;
  f16* K2h = (f16*)K2;

  const int NB = 256;
  const int Bn = 32;

  // --- input batch-norm (C=1, no affine) ---
  {
    int ss = 64 * 64 * 64;
    stats1<<<dim3(NB, 1), 256, 0, stream>>>(x, part, Bn, 1, ss, NB);
    stats2<<<1, 256, 0, stream>>>(part, stats, NB, 1.0f / (float)(Bn * (long)ss));
    int gx = (ss + 255) / 256;
    bn_apply<<<dim3(gx, Bn), 256, 0, stream>>>(x, A, stats, nullptr, nullptr, nullptr, 1, ss, 0);
  }

  const int SINs[5]  = {1, 8, 16, 16, 16};
  const int SOUTs[5] = {8, 16, 16, 16, 10};
  const int VECs[5]  = {4, 12, 16, 16, 13};
  const int ISs[5]   = {64, 35, 21, 14, 10};
  const int VSs[5]   = {33, 19, 12, 8, 6};
  const int OSs[5]   = {35, 21, 14, 10, 8};
  const int MFMA_ON[5] = {1, 1, 1, 1, 0};      // block 4 stays fp32 (tiny; control)
  const int CP8s[5]  = {8, 24, 24, 24, 0};     // block 1 uses the PROVEN CP8=24 instantiation
  const int CHKs[5]  = {8, 16, 32, 32, 32};    // VT fits: 18.4M / 21.1M / 16.9M / 9.8M f16

  float* sbuf = A;
  for (int i = 0; i < 5; ++i) {
    float* obuf = (i % 2 == 0) ? Bb : A;
    int IS = ISs[i], VS = VSs[i], OS = OSs[i];
    int VEC = VECs[i], SIN = SINs[i], SOUT = SOUTs[i];

    { int t = SIN * 125 * VEC * 3;
      build_k1<<<(t + 255) / 256, 256, 0, stream>>>(w1[i], K1, VEC, SIN); }

    if (!MFMA_ON[i]) {
      // -------- fp32 path (block 4) --------
      { int t = Bn * VS * VS * VS; int g = (t + 255) / 256;
        conv1_k<16, 13><<<g, 256, 0, stream>>>(sbuf, K1, V, Bn, IS, VS); }
      { int t = 125 * VEC * 12 * SOUT;
        build_k2<<<(t + 255) / 256, 256, 0, stream>>>(wA[i], wB[i], K2, VEC, SOUT); }
      { int t = Bn * OS * OS * OS; int g = (t + 255) / 256;
        conv2_k<13, 10><<<g, 256, 0, stream>>>(V, K2, obuf, Bn, VS, OS); }
    } else {
      // -------- MFMA path (blocks 0..3) --------
      int CP8 = CP8s[i], CP = CP8 * 8;
      int CHK = CHKs[i];
      int XG = (OS + 15) / 16;
      { int t = 125 * 16 * CP;
        build_k2b<<<(t + 255) / 256, 256, 0, stream>>>(wA[i], wB[i], K2h, VEC, SOUT, CP); }
      for (int b0 = 0; b0 < Bn; b0 += CHK) {
        int bc = CHK;
        const float* sp = sbuf + (long)b0 * SIN * IS * IS * IS;
        float* op = obuf + (long)b0 * SOUT * OS * OS * OS;
        int t1 = bc * VS * VS * VS;
        int g1 = (t1 + 255) / 256;
        long waves = (long)bc * OS * OS * XG;
        int g2 = (int)((waves * 64 + 255) / 256);
        switch (i) {
          case 0:
            conv1_vt<1, 4, 8><<<g1, 256, 0, stream>>>(sp, K1, VT, bc, IS, VS);
            conv2_mfma<8, 8><<<g2, 256, 0, stream>>>(VT, K2h, op, bc, VS, OS, XG);
            break;
          case 1:
            conv1_vt<8, 12, 24><<<g1, 256, 0, stream>>>(sp, K1, VT, bc, IS, VS);
            conv2_mfma<24, 16><<<g2, 256, 0, stream>>>(VT, K2h, op, bc, VS, OS, XG);
            break;
          case 2:
            conv1_vt<16, 16, 24><<<g1, 256, 0, stream>>>(sp, K1, VT, bc, IS, VS);
            conv2_mfma<24, 16><<<g2, 256, 0, stream>>>(VT, K2h, op, bc, VS, OS, XG);
            break;
          case 3:
            conv1_vt<16, 16, 24><<<g1, 256, 0, stream>>>(sp, K1, VT, bc, IS, VS);
            conv2_mfma<24, 16><<<g2, 256, 0, stream>>>(VT, K2h, op, bc, VS, OS, XG);
            break;
        }
      }
    }

    { int ss = OS * OS * OS;
      stats1<<<dim3(NB, SOUT), 256, 0, stream>>>(obuf, part, Bn, SOUT, ss, NB);
      stats2<<<SOUT, 256, 0, stream>>>(part, stats, NB, 1.0f / (float)((long)Bn * ss));
      int gx = (ss + 255) / 256;
      bn_apply<<<dim3(gx, Bn * SOUT), 256, 0, stream>>>(obuf, obuf, stats, gam[i], bet[i],
                                                        bias[i], SOUT, ss, (i < 4) ? 1 : 0);
    }
    sbuf = obuf;
  }

  pool_k<<<Bn * 10, 256, 0, stream>>>(sbuf, pooled, 8 * 8 * 8);
  final_bn<<<1, 64, 0, stream>>>(pooled, gamma_out, beta_out, out, Bn, 10);
}

// Round 6
// 6481.825 us; speedup vs baseline: 1.6916x; 1.6916x over previous
//
#include <hip/hip_runtime.h>
#include <math.h>

#define EPSF 1e-5f

typedef _Float16 f16;
typedef __attribute__((ext_vector_type(8))) _Float16 f16x8;
typedef __attribute__((ext_vector_type(4))) float f32x4;

// ---------------- basis helpers ----------------
__device__ __forceinline__ void tap_geom(int tap, float hats[4], float xh[3], float& mask) {
  int d = tap / 25, h = (tap / 5) % 5, w = tap % 5;
  float X = (float)(d - 2), Y = (float)(h - 2), Z = (float)(w - 2);
  float r = sqrtf(X * X + Y * Y + Z * Z);
#pragma unroll
  for (int k = 0; k < 4; ++k) hats[k] = fmaxf(1.0f - fabsf(r - (float)k), 0.0f);
  float inv = (r > 0.0f) ? (1.0f / r) : 0.0f;
  xh[0] = X * inv; xh[1] = Y * inv; xh[2] = Z * inv;
  mask = (r > 0.0f) ? 1.0f : 0.0f;
}

// K1 layout: [(i*125 + tap)*VEC*3 + (o*3+j)]  (fp32)
__global__ void build_k1(const float* __restrict__ w1, float* __restrict__ K1,
                         int VEC, int SIN) {
  int OC3 = VEC * 3;
  int total = SIN * 125 * OC3;
  for (int idx = blockIdx.x * blockDim.x + threadIdx.x; idx < total;
       idx += gridDim.x * blockDim.x) {
    int oc = idx % OC3;
    int tap = (idx / OC3) % 125;
    int i = idx / (OC3 * 125);
    int o = oc / 3, j = oc % 3;
    float hats[4], xh[3], mask;
    tap_geom(tap, hats, xh, mask);
    float R = 0.f;
#pragma unroll
    for (int k = 0; k < 4; ++k) R += w1[(o * SIN + i) * 4 + k] * hats[k];
    K1[idx] = xh[j] * R;
  }
}

// ---- fp32 K2 (for fp32 path): [((tap*VEC + cv)*12 + comp)*SOUT + o] ----
__global__ void build_k2(const float* __restrict__ wA, const float* __restrict__ wB,
                         float* __restrict__ K2, int VEC, int SOUT) {
  int total = 125 * VEC * 12 * SOUT;
  for (int idx = blockIdx.x * blockDim.x + threadIdx.x; idx < total;
       idx += gridDim.x * blockDim.x) {
    int o = idx % SOUT;
    int comp = (idx / SOUT) % 12;
    int cv = (idx / (SOUT * 12)) % VEC;
    int tap = idx / (SOUT * 12 * VEC);
    float hats[4], xh[3], mask;
    tap_geom(tap, hats, xh, mask);
    float val;
    if (comp < 3) {
      float RA = 0.f;
#pragma unroll
      for (int k = 0; k < 4; ++k) RA += wA[(o * VEC + cv) * 4 + k] * hats[k];
      val = RA * xh[comp];
    } else {
      int ij = comp - 3;
      int ii = ij / 3, jj = ij % 3;
      float RB[3];
#pragma unroll
      for (int m = 0; m < 3; ++m) {
        float r = 0.f;
#pragma unroll
        for (int k = 0; k < 4; ++k) r += wB[((o * VEC + cv) * 3 + m) * 4 + k] * hats[k];
        RB[m] = r;
      }
      float a0 = (ii == jj) ? 1.0f : 0.0f;
      float a1 = 0.0f;
      if (ii != jj) {
        int l = 3 - ii - jj;
        float sgn = (((jj - ii + 3) % 3) == 1) ? 1.0f : -1.0f;
        a1 = sgn * xh[l];
      }
      float a2 = xh[ii] * xh[jj] - ((ii == jj) ? (mask / 3.0f) : 0.0f);
      val = RB[0] * a0 + RB[1] * a1 + RB[2] * a2;
    }
    K2[idx] = val;
  }
}

// ---- MFMA K2 (f16): [tap][n=16][C_pad] ----
__global__ void build_k2b(const float* __restrict__ wA, const float* __restrict__ wB,
                          f16* __restrict__ K2, int VEC, int SOUT, int CP) {
  int total = 125 * 16 * CP;
  for (int idx = blockIdx.x * blockDim.x + threadIdx.x; idx < total;
       idx += gridDim.x * blockDim.x) {
    int c = idx % CP;
    int n = (idx / CP) % 16;
    int tap = idx / (CP * 16);
    float val = 0.f;
    if (n < SOUT && c < VEC * 12) {
      float hats[4], xh[3], mask;
      tap_geom(tap, hats, xh, mask);
      if (c < VEC * 3) {
        int cv = c / 3, j = c % 3;
        float RA = 0.f;
#pragma unroll
        for (int k = 0; k < 4; ++k) RA += wA[(n * VEC + cv) * 4 + k] * hats[k];
        val = RA * xh[j];
      } else {
        int q = c - VEC * 3;
        int cv = q / 9, ij = q % 9;
        int ii = ij / 3, jj = ij % 3;
        float RB[3];
#pragma unroll
        for (int m = 0; m < 3; ++m) {
          float r = 0.f;
#pragma unroll
          for (int k = 0; k < 4; ++k) r += wB[((n * VEC + cv) * 3 + m) * 4 + k] * hats[k];
          RB[m] = r;
        }
        float a0 = (ii == jj) ? 1.0f : 0.0f;
        float a1 = 0.0f;
        if (ii != jj) {
          int l = 3 - ii - jj;
          float sgn = (((jj - ii + 3) % 3) == 1) ? 1.0f : -1.0f;
          a1 = sgn * xh[l];
        }
        float a2 = xh[ii] * xh[jj] - ((ii == jj) ? (mask / 3.0f) : 0.0f);
        val = RB[0] * a0 + RB[1] * a1 + RB[2] * a2;
      }
    }
    K2[idx] = (f16)val;
  }
}

// ---------------- fp32 conv1 (V layout [b][oc][pos]) ----------------
template <int SIN, int VEC>
__global__ __launch_bounds__(256) void conv1_k(const float* __restrict__ s,
                                               const float* __restrict__ K1,
                                               float* __restrict__ v, int B, int IS, int OS) {
  constexpr int OC3 = VEC * 3;
  int iss = IS * IS * IS;
  int oss = OS * OS * OS;
  int total = B * oss;
  for (int idx = blockIdx.x * blockDim.x + threadIdx.x; idx < total;
       idx += gridDim.x * blockDim.x) {
    int x = idx % OS;
    int y = (idx / OS) % OS;
    int z = (idx / (OS * OS)) % OS;
    int b = idx / oss;
    float acc[OC3];
#pragma unroll
    for (int o = 0; o < OC3; ++o) acc[o] = 0.f;
    for (int i = 0; i < SIN; ++i) {
      const float* sb = s + ((long)b * SIN + i) * iss;
      for (int d = 0; d < 5; ++d) {
        int iz = 2 * z - 3 + d;
        if ((unsigned)iz >= (unsigned)IS) continue;
        for (int h = 0; h < 5; ++h) {
          int iy = 2 * y - 3 + h;
          if ((unsigned)iy >= (unsigned)IS) continue;
#pragma unroll
          for (int w = 0; w < 5; ++w) {
            int ix = 2 * x - 3 + w;
            if ((unsigned)ix >= (unsigned)IS) continue;
            float sv = sb[(iz * IS + iy) * IS + ix];
            const float* kp = K1 + (i * 125 + (d * 25 + h * 5 + w)) * OC3;
#pragma unroll
            for (int o = 0; o < OC3; ++o) acc[o] = fmaf(sv, kp[o], acc[o]);
          }
        }
      }
    }
    int p = (z * OS + y) * OS + x;
#pragma unroll
    for (int oc = 0; oc < OC3; ++oc) v[((long)b * OC3 + oc) * oss + p] = acc[oc];
  }
}

// ---------------- fp32 conv2 (t on the fly) ----------------
template <int VEC, int SOUT>
__global__ __launch_bounds__(256) void conv2_k(const float* __restrict__ v,
                                               const float* __restrict__ K2,
                                               float* __restrict__ out, int B, int IS, int OS) {
  int iss = IS * IS * IS;
  int oss = OS * OS * OS;
  int total = B * oss;
  for (int idx = blockIdx.x * blockDim.x + threadIdx.x; idx < total;
       idx += gridDim.x * blockDim.x) {
    int x = idx % OS;
    int y = (idx / OS) % OS;
    int z = (idx / (OS * OS)) % OS;
    int b = idx / oss;
    float acc[SOUT];
#pragma unroll
    for (int o = 0; o < SOUT; ++o) acc[o] = 0.f;
    for (int d = 0; d < 5; ++d) {
      int iz = z - 3 + d;
      if ((unsigned)iz >= (unsigned)IS) continue;
      for (int h = 0; h < 5; ++h) {
        int iy = y - 3 + h;
        if ((unsigned)iy >= (unsigned)IS) continue;
        for (int w = 0; w < 5; ++w) {
          int ix = x - 3 + w;
          if ((unsigned)ix >= (unsigned)IS) continue;
          int tap = d * 25 + h * 5 + w;
          int ppos = (iz * IS + iy) * IS + ix;
          const float* kt = K2 + (long)tap * (VEC * 12 * SOUT);
          const float* vb = v + ((long)b * VEC * 3) * iss + ppos;
#pragma unroll 1
          for (int cv = 0; cv < VEC; ++cv) {
            float v0 = vb[(cv * 3 + 0) * iss];
            float v1 = vb[(cv * 3 + 1) * iss];
            float v2 = vb[(cv * 3 + 2) * iss];
            const float* kp = kt + cv * (12 * SOUT);
            float vals[12] = {v0, v1, v2,
                              v0 * v0, v0 * v1, v0 * v2,
                              v1 * v0, v1 * v1, v1 * v2,
                              v2 * v0, v2 * v1, v2 * v2};
#pragma unroll
            for (int comp = 0; comp < 12; ++comp) {
              float vv = vals[comp];
#pragma unroll
              for (int o = 0; o < SOUT; ++o)
                acc[o] = fmaf(vv, kp[comp * SOUT + o], acc[o]);
            }
          }
        }
      }
    }
    int p = (z * OS + y) * OS + x;
#pragma unroll
    for (int o = 0; o < SOUT; ++o) out[((long)b * SOUT + o) * oss + p] = acc[o];
  }
}

// ---------------- MFMA conv1: fp32 conv fused with f16 vt build ----------------
// VT[b][z][y][cg][x][8]; channels c=cg*8+e: c<OC3: v; OC3<=c<VEC*12: t; else 0.
template <int SIN, int VEC, int CP8>
__global__ __launch_bounds__(256) void conv1_vt(const float* __restrict__ s,
                                                const float* __restrict__ K1,
                                                f16* __restrict__ VT,
                                                int Bc, int IS, int OS) {
  constexpr int OC3 = VEC * 3;
  int iss = IS * IS * IS;
  int oss = OS * OS * OS;
  int total = Bc * oss;
  for (int idx = blockIdx.x * blockDim.x + threadIdx.x; idx < total;
       idx += gridDim.x * blockDim.x) {
    int x = idx % OS;
    int y = (idx / OS) % OS;
    int z = (idx / (OS * OS)) % OS;
    int b = idx / oss;
    float acc[OC3];
#pragma unroll
    for (int o = 0; o < OC3; ++o) acc[o] = 0.f;
    for (int i = 0; i < SIN; ++i) {
      const float* sb = s + ((long)b * SIN + i) * iss;
      for (int d = 0; d < 5; ++d) {
        int iz = 2 * z - 3 + d;
        if ((unsigned)iz >= (unsigned)IS) continue;
        for (int h = 0; h < 5; ++h) {
          int iy = 2 * y - 3 + h;
          if ((unsigned)iy >= (unsigned)IS) continue;
#pragma unroll
          for (int w = 0; w < 5; ++w) {
            int ix = 2 * x - 3 + w;
            if ((unsigned)ix >= (unsigned)IS) continue;
            float sv = sb[(iz * IS + iy) * IS + ix];
            const float* kp = K1 + (i * 125 + (d * 25 + h * 5 + w)) * OC3;
#pragma unroll
            for (int o = 0; o < OC3; ++o) acc[o] = fmaf(sv, kp[o], acc[o]);
          }
        }
      }
    }
    long rowbase = (((long)(b * OS + z) * OS + y) * CP8) * (long)OS * 8 + (long)x * 8;
#pragma unroll
    for (int cg = 0; cg < CP8; ++cg) {
      f16x8 pack;
#pragma unroll
      for (int e = 0; e < 8; ++e) {
        int c = cg * 8 + e;
        float v;
        if (c < OC3) v = acc[c];
        else if (c < VEC * 12) {
          int q = c - OC3;
          int cv = q / 9, r9 = q % 9;
          v = acc[cv * 3 + r9 / 3] * acc[cv * 3 + r9 % 3];
        } else v = 0.f;
        pack[e] = (f16)v;
      }
      *(f16x8*)(VT + rowbase + (long)cg * OS * 8) = pack;
    }
  }
}

// ---------------- MFMA conv2 v2: z-tiled wave, input-plane loop ----------------
// One wave: ZT z-outputs x 16 x-positions x 16 out channels at fixed (b,y,xg).
// Per (h,w,ks): load 5 B-frags (d=0..4) + ZT+4 A-frags (input planes), then
// up to 5*ZT independent MFMAs — deep ILP, 2-3x fewer loads than v1.
template <int CP8, int SOUT, int ZT>
__global__ __launch_bounds__(256) void conv2_mfma(const f16* __restrict__ VT,
                                                  const f16* __restrict__ K2,
                                                  float* __restrict__ out,
                                                  int Bc, int IS, int OS, int XG, int ZG) {
  constexpr int KS = CP8 / 4;      // K-steps of 32 channels
  constexpr int CP = CP8 * 8;
  constexpr int NU = ZT + 4;       // input planes touched: zi in [z0-3, z0+ZT]
  int wid = (int)((blockIdx.x * (long)blockDim.x + threadIdx.x) >> 6);
  int lane = threadIdx.x & 63;
  int total = Bc * ZG * OS * XG;
  if (wid >= total) return;
  int xg = wid % XG;
  int y  = (wid / XG) % OS;
  int zg = (wid / (XG * OS)) % ZG;
  int b  = wid / (XG * OS * ZG);
  int z0 = zg * ZT;
  int x0 = xg * 16;
  int lm = lane & 15;   // A row (x offset) / B row (out channel)
  int g  = lane >> 4;   // k-group

  f32x4 acc[ZT];
#pragma unroll
  for (int t = 0; t < ZT; ++t) acc[t] = (f32x4){0.f, 0.f, 0.f, 0.f};

  const f16* bp = K2 + (long)lm * CP + g * 8;

  for (int h = 0; h < 5; ++h) {
    int yi = y - 3 + h;
    if ((unsigned)yi >= (unsigned)IS) continue;
    const f16* base[NU];
    bool zok[NU];
#pragma unroll
    for (int u = 0; u < NU; ++u) {
      int zi = z0 - 3 + u;
      zok[u] = (unsigned)zi < (unsigned)IS;
      int zc = zok[u] ? zi : 0;
      base[u] = VT + (((long)(b * IS + zc) * IS + yi) * CP8) * (long)IS * 8;
    }
#pragma unroll 1
    for (int w = 0; w < 5; ++w) {
      int xi = x0 + lm - 3 + w;
      bool xok = (unsigned)xi < (unsigned)IS;
      const f16* tb = bp + ((long)(h * 5 + w) * 16) * CP;
#pragma unroll
      for (int ks = 0; ks < KS; ++ks) {
        f16x8 bf[5];
#pragma unroll
        for (int d = 0; d < 5; ++d)
          bf[d] = *(const f16x8*)(tb + (long)d * (25 * 16) * CP + ks * 32);
        f16x8 af[NU];
#pragma unroll
        for (int u = 0; u < NU; ++u) {
          af[u] = (f16x8){};
          if (zok[u] && xok)
            af[u] = *(const f16x8*)(base[u] + ((ks * 4 + g) * IS + xi) * 8);
        }
#pragma unroll
        for (int u = 0; u < NU; ++u) {
#pragma unroll
          for (int t = 0; t < ZT; ++t) {
            int d = u - t;                 // compile-time constant per unrolled (u,t)
            if (d >= 0 && d <= 4)
              acc[t] = __builtin_amdgcn_mfma_f32_16x16x32_f16(af[u], bf[d], acc[t], 0, 0, 0);
          }
        }
      }
    }
  }
  // D: col(out ch) = lane&15, row(x) = 4*(lane>>4)+r
  if (lm < SOUT) {
    int oss = OS * OS * OS;
#pragma unroll
    for (int t = 0; t < ZT; ++t) {
      int z = z0 + t;
      if (z < OS) {
        float* op = out + ((long)b * SOUT + lm) * oss + (z * OS + y) * OS;
#pragma unroll
        for (int r = 0; r < 4; ++r) {
          int xm = x0 + g * 4 + r;
          if (xm < OS) op[xm] = acc[t][r];
        }
      }
    }
  }
}

// ---------------- batch-norm reductions (two-stage, deterministic) ----------------
__global__ void stats1(const float* __restrict__ a, float* __restrict__ part,
                       int B, int C, int ss, int nblk) {
  int c = blockIdx.y;
  int tid = threadIdx.x;
  float s = 0.f, s2 = 0.f;
  for (int b = 0; b < B; ++b) {
    const float* ab = a + ((long)b * C + c) * ss;
    for (int p = blockIdx.x * blockDim.x + tid; p < ss; p += nblk * blockDim.x) {
      float x = ab[p];
      s += x;
      s2 += x * x;
    }
  }
  __shared__ float sh[256], sh2[256];
  sh[tid] = s; sh2[tid] = s2;
  __syncthreads();
  for (int off = 128; off > 0; off >>= 1) {
    if (tid < off) { sh[tid] += sh[tid + off]; sh2[tid] += sh2[tid + off]; }
    __syncthreads();
  }
  if (tid == 0) {
    part[(c * nblk + blockIdx.x) * 2 + 0] = sh[0];
    part[(c * nblk + blockIdx.x) * 2 + 1] = sh2[0];
  }
}

__global__ void stats2(const float* __restrict__ part, float* __restrict__ stats,
                       int nblk, float invn) {
  int c = blockIdx.x;
  int tid = threadIdx.x;
  float s = 0.f, s2 = 0.f;
  for (int i = tid; i < nblk; i += blockDim.x) {
    s += part[(c * nblk + i) * 2 + 0];
    s2 += part[(c * nblk + i) * 2 + 1];
  }
  __shared__ float sh[256], sh2[256];
  sh[tid] = s; sh2[tid] = s2;
  __syncthreads();
  for (int off = 128; off > 0; off >>= 1) {
    if (tid < off) { sh[tid] += sh[tid + off]; sh2[tid] += sh2[tid + off]; }
    __syncthreads();
  }
  if (tid == 0) {
    float m = sh[0] * invn;
    float var = sh2[0] * invn - m * m;
    stats[c * 2 + 0] = m;
    stats[c * 2 + 1] = 1.0f / sqrtf(var + EPSF);
  }
}

__global__ void bn_apply(const float* __restrict__ in, float* __restrict__ out,
                         const float* __restrict__ stats, const float* __restrict__ g,
                         const float* __restrict__ be, const float* __restrict__ bias,
                         int C, int ss, int relu) {
  int bc = blockIdx.y;
  int c = bc % C;
  float m = stats[c * 2 + 0];
  float r = stats[c * 2 + 1];
  float ga = g ? g[c] : 1.f;
  float bb = be ? be[c] : 0.f;
  float bi = bias ? bias[c] : 0.f;
  const float* ip = in + (long)bc * ss;
  float* op = out + (long)bc * ss;
  for (int p = blockIdx.x * blockDim.x + threadIdx.x; p < ss; p += gridDim.x * blockDim.x) {
    float xn = (ip[p] - m) * r * ga + bb;
    if (relu) xn = fmaxf(xn + bi, 0.f);
    op[p] = xn;
  }
}

// ---------------- pooling + final batch-norm ----------------
__global__ void pool_k(const float* __restrict__ in, float* __restrict__ pooled, int ss) {
  int bc = blockIdx.x;
  int tid = threadIdx.x;
  const float* p = in + (long)bc * ss;
  float s = 0.f;
  for (int e = tid; e < ss; e += blockDim.x) s += p[e];
  __shared__ float sh[256];
  sh[tid] = s;
  __syncthreads();
  for (int off = 128; off > 0; off >>= 1) {
    if (tid < off) sh[tid] += sh[tid + off];
    __syncthreads();
  }
  if (tid == 0) pooled[bc] = sh[0] / (float)ss;
}

__global__ void final_bn(const float* __restrict__ pooled, const float* __restrict__ g,
                         const float* __restrict__ be, float* __restrict__ out,
                         int B, int C) {
  int tid = threadIdx.x;
  __shared__ float mv[16][2];
  if (tid < C) {
    float s = 0.f, s2 = 0.f;
    for (int b = 0; b < B; ++b) {
      float x = pooled[b * C + tid];
      s += x;
      s2 += x * x;
    }
    float m = s / (float)B;
    float var = s2 / (float)B - m * m;
    mv[tid][0] = m;
    mv[tid][1] = 1.0f / sqrtf(var + EPSF);
  }
  __syncthreads();
  for (int i = tid; i < B * C; i += blockDim.x) {
    int c = i % C;
    out[i] = g[c] * (pooled[i] - mv[c][0]) * mv[c][1] + be[c];
  }
}

// ---------------- host ----------------
extern "C" void kernel_launch(void* const* d_in, const int* in_sizes, int n_in,
                              void* d_out, int out_size, void* d_ws, size_t ws_size,
                              hipStream_t stream) {
  (void)in_sizes; (void)n_in; (void)out_size; (void)ws_size;
  const float* x = (const float*)d_in[0];
  const float* w1[5]; const float* wA[5]; const float* wB[5];
  const float* bias[5]; const float* gam[5]; const float* bet[5];
  for (int i = 0; i < 5; ++i) {
    w1[i]  = (const float*)d_in[1 + i * 6 + 0];
    wA[i]  = (const float*)d_in[1 + i * 6 + 1];
    wB[i]  = (const float*)d_in[1 + i * 6 + 2];
    bias[i]= (const float*)d_in[1 + i * 6 + 3];
    gam[i] = (const float*)d_in[1 + i * 6 + 4];
    bet[i] = (const float*)d_in[1 + i * 6 + 5];
  }
  const float* gamma_out = (const float*)d_in[31];
  const float* beta_out  = (const float*)d_in[32];
  float* out = (float*)d_out;

  // workspace carve — identical to round-4/5 (proven fit ~135 MB)
  float* A     = (float*)d_ws;            // 8,388,608
  float* Bb    = A + 8388608;             // 10,976,000
  float* V     = Bb + 10976000;           // 13,799,808 floats (fp32 V / f16 VT = 27.6M f16)
  float* K1    = V + 13799808;            // 96,000
  float* K2    = K1 + 96000;              // 384,000 floats (fp32 K2 / f16 K2h)
  float* part  = K2 + 384000;             // 8,192
  float* stats = part + 16 * 256 * 2;
  float* pooled= stats + 64;
  f16* VT  = (f16*)V;
  f16* K2h = (f16*)K2;

  const int NB = 256;
  const int Bn = 32;
  const int ZT = 4;

  // --- input batch-norm (C=1, no affine) ---
  {
    int ss = 64 * 64 * 64;
    stats1<<<dim3(NB, 1), 256, 0, stream>>>(x, part, Bn, 1, ss, NB);
    stats2<<<1, 256, 0, stream>>>(part, stats, NB, 1.0f / (float)(Bn * (long)ss));
    int gx = (ss + 255) / 256;
    bn_apply<<<dim3(gx, Bn), 256, 0, stream>>>(x, A, stats, nullptr, nullptr, nullptr, 1, ss, 0);
  }

  const int SINs[5]  = {1, 8, 16, 16, 16};
  const int SOUTs[5] = {8, 16, 16, 16, 10};
  const int VECs[5]  = {4, 12, 16, 16, 13};
  const int ISs[5]   = {64, 35, 21, 14, 10};
  const int VSs[5]   = {33, 19, 12, 8, 6};
  const int OSs[5]   = {35, 21, 14, 10, 8};
  const int MFMA_ON[5] = {1, 1, 1, 1, 0};      // block 4 stays fp32 (tiny; control)
  const int CP8s[5]  = {8, 24, 24, 24, 0};
  const int CHKs[5]  = {8, 16, 32, 32, 32};

  float* sbuf = A;
  for (int i = 0; i < 5; ++i) {
    float* obuf = (i % 2 == 0) ? Bb : A;
    int IS = ISs[i], VS = VSs[i], OS = OSs[i];
    int VEC = VECs[i], SIN = SINs[i], SOUT = SOUTs[i];

    { int t = SIN * 125 * VEC * 3;
      build_k1<<<(t + 255) / 256, 256, 0, stream>>>(w1[i], K1, VEC, SIN); }

    if (!MFMA_ON[i]) {
      // -------- fp32 path (block 4) --------
      { int t = Bn * VS * VS * VS; int g = (t + 255) / 256;
        conv1_k<16, 13><<<g, 256, 0, stream>>>(sbuf, K1, V, Bn, IS, VS); }
      { int t = 125 * VEC * 12 * SOUT;
        build_k2<<<(t + 255) / 256, 256, 0, stream>>>(wA[i], wB[i], K2, VEC, SOUT); }
      { int t = Bn * OS * OS * OS; int g = (t + 255) / 256;
        conv2_k<13, 10><<<g, 256, 0, stream>>>(V, K2, obuf, Bn, VS, OS); }
    } else {
      // -------- MFMA path (blocks 0..3) --------
      int CP8 = CP8s[i], CP = CP8 * 8;
      int CHK = CHKs[i];
      int XG = (OS + 15) / 16;
      int ZG = (OS + ZT - 1) / ZT;
      { int t = 125 * 16 * CP;
        build_k2b<<<(t + 255) / 256, 256, 0, stream>>>(wA[i], wB[i], K2h, VEC, SOUT, CP); }
      for (int b0 = 0; b0 < Bn; b0 += CHK) {
        int bc = CHK;
        const float* sp = sbuf + (long)b0 * SIN * IS * IS * IS;
        float* op = obuf + (long)b0 * SOUT * OS * OS * OS;
        int t1 = bc * VS * VS * VS;
        int g1 = (t1 + 255) / 256;
        long waves = (long)bc * ZG * OS * XG;
        int g2 = (int)((waves * 64 + 255) / 256);
        switch (i) {
          case 0:
            conv1_vt<1, 4, 8><<<g1, 256, 0, stream>>>(sp, K1, VT, bc, IS, VS);
            conv2_mfma<8, 8, ZT><<<g2, 256, 0, stream>>>(VT, K2h, op, bc, VS, OS, XG, ZG);
            break;
          case 1:
            conv1_vt<8, 12, 24><<<g1, 256, 0, stream>>>(sp, K1, VT, bc, IS, VS);
            conv2_mfma<24, 16, ZT><<<g2, 256, 0, stream>>>(VT, K2h, op, bc, VS, OS, XG, ZG);
            break;
          case 2:
            conv1_vt<16, 16, 24><<<g1, 256, 0, stream>>>(sp, K1, VT, bc, IS, VS);
            conv2_mfma<24, 16, ZT><<<g2, 256, 0, stream>>>(VT, K2h, op, bc, VS, OS, XG, ZG);
            break;
          case 3:
            conv1_vt<16, 16, 24><<<g1, 256, 0, stream>>>(sp, K1, VT, bc, IS, VS);
            conv2_mfma<24, 16, ZT><<<g2, 256, 0, stream>>>(VT, K2h, op, bc, VS, OS, XG, ZG);
            break;
        }
      }
    }

    { int ss = OS * OS * OS;
      stats1<<<dim3(NB, SOUT), 256, 0, stream>>>(obuf, part, Bn, SOUT, ss, NB);
      stats2<<<SOUT, 256, 0, stream>>>(part, stats, NB, 1.0f / (float)((long)Bn * ss));
      int gx = (ss + 255) / 256;
      bn_apply<<<dim3(gx, Bn * SOUT), 256, 0, stream>>>(obuf, obuf, stats, gam[i], bet[i],
                                                        bias[i], SOUT, ss, (i < 4) ? 1 : 0);
    }
    sbuf = obuf;
  }

  pool_k<<<Bn * 10, 256, 0, stream>>>(sbuf, pooled, 8 * 8 * 8);
  final_bn<<<1, 64, 0, stream>>>(pooled, gamma_out, beta_out, out, Bn, 10);
}

// Round 7
// 5645.135 us; speedup vs baseline: 1.9423x; 1.1482x over previous
//
#include <hip/hip_runtime.h>
#include <math.h>

#define EPSF 1e-5f

typedef _Float16 f16;
typedef __attribute__((ext_vector_type(8))) _Float16 f16x8;
typedef __attribute__((ext_vector_type(4))) float f32x4;

// ---------------- basis helpers ----------------
__device__ __forceinline__ void tap_geom(int tap, float hats[4], float xh[3], float& mask) {
  int d = tap / 25, h = (tap / 5) % 5, w = tap % 5;
  float X = (float)(d - 2), Y = (float)(h - 2), Z = (float)(w - 2);
  float r = sqrtf(X * X + Y * Y + Z * Z);
#pragma unroll
  for (int k = 0; k < 4; ++k) hats[k] = fmaxf(1.0f - fabsf(r - (float)k), 0.0f);
  float inv = (r > 0.0f) ? (1.0f / r) : 0.0f;
  xh[0] = X * inv; xh[1] = Y * inv; xh[2] = Z * inv;
  mask = (r > 0.0f) ? 1.0f : 0.0f;
}

// K1 layout: [(i*125 + tap)*VEC*3 + (o*3+j)]  (fp32)
__global__ void build_k1(const float* __restrict__ w1, float* __restrict__ K1,
                         int VEC, int SIN) {
  int OC3 = VEC * 3;
  int total = SIN * 125 * OC3;
  for (int idx = blockIdx.x * blockDim.x + threadIdx.x; idx < total;
       idx += gridDim.x * blockDim.x) {
    int oc = idx % OC3;
    int tap = (idx / OC3) % 125;
    int i = idx / (OC3 * 125);
    int o = oc / 3, j = oc % 3;
    float hats[4], xh[3], mask;
    tap_geom(tap, hats, xh, mask);
    float R = 0.f;
#pragma unroll
    for (int k = 0; k < 4; ++k) R += w1[(o * SIN + i) * 4 + k] * hats[k];
    K1[idx] = xh[j] * R;
  }
}

// ---- MFMA K2 (f16): [tap][n=16][C_pad] ----
__global__ void build_k2b(const float* __restrict__ wA, const float* __restrict__ wB,
                          f16* __restrict__ K2, int VEC, int SOUT, int CP) {
  int total = 125 * 16 * CP;
  for (int idx = blockIdx.x * blockDim.x + threadIdx.x; idx < total;
       idx += gridDim.x * blockDim.x) {
    int c = idx % CP;
    int n = (idx / CP) % 16;
    int tap = idx / (CP * 16);
    float val = 0.f;
    if (n < SOUT && c < VEC * 12) {
      float hats[4], xh[3], mask;
      tap_geom(tap, hats, xh, mask);
      if (c < VEC * 3) {
        int cv = c / 3, j = c % 3;
        float RA = 0.f;
#pragma unroll
        for (int k = 0; k < 4; ++k) RA += wA[(n * VEC + cv) * 4 + k] * hats[k];
        val = RA * xh[j];
      } else {
        int q = c - VEC * 3;
        int cv = q / 9, ij = q % 9;
        int ii = ij / 3, jj = ij % 3;
        float RB[3];
#pragma unroll
        for (int m = 0; m < 3; ++m) {
          float r = 0.f;
#pragma unroll
          for (int k = 0; k < 4; ++k) r += wB[((n * VEC + cv) * 3 + m) * 4 + k] * hats[k];
          RB[m] = r;
        }
        float a0 = (ii == jj) ? 1.0f : 0.0f;
        float a1 = 0.0f;
        if (ii != jj) {
          int l = 3 - ii - jj;
          float sgn = (((jj - ii + 3) % 3) == 1) ? 1.0f : -1.0f;
          a1 = sgn * xh[l];
        }
        float a2 = xh[ii] * xh[jj] - ((ii == jj) ? (mask / 3.0f) : 0.0f);
        val = RB[0] * a0 + RB[1] * a1 + RB[2] * a2;
      }
    }
    K2[idx] = (f16)val;
  }
}

// ---------------- MFMA conv1: fp32 conv fused with f16 vt build ----------------
// VT[b][z][y][cg][x][8]; channels c=cg*8+e: c<OC3: v; OC3<=c<VEC*12: t; else 0.
template <int SIN, int VEC, int CP8>
__global__ __launch_bounds__(256) void conv1_vt(const float* __restrict__ s,
                                                const float* __restrict__ K1,
                                                f16* __restrict__ VT,
                                                int Bc, int IS, int OS) {
  constexpr int OC3 = VEC * 3;
  int iss = IS * IS * IS;
  int oss = OS * OS * OS;
  int total = Bc * oss;
  for (int idx = blockIdx.x * blockDim.x + threadIdx.x; idx < total;
       idx += gridDim.x * blockDim.x) {
    int x = idx % OS;
    int y = (idx / OS) % OS;
    int z = (idx / (OS * OS)) % OS;
    int b = idx / oss;
    float acc[OC3];
#pragma unroll
    for (int o = 0; o < OC3; ++o) acc[o] = 0.f;
    for (int i = 0; i < SIN; ++i) {
      const float* sb = s + ((long)b * SIN + i) * iss;
      for (int d = 0; d < 5; ++d) {
        int iz = 2 * z - 3 + d;
        if ((unsigned)iz >= (unsigned)IS) continue;
        for (int h = 0; h < 5; ++h) {
          int iy = 2 * y - 3 + h;
          if ((unsigned)iy >= (unsigned)IS) continue;
#pragma unroll
          for (int w = 0; w < 5; ++w) {
            int ix = 2 * x - 3 + w;
            if ((unsigned)ix >= (unsigned)IS) continue;
            float sv = sb[(iz * IS + iy) * IS + ix];
            const float* kp = K1 + (i * 125 + (d * 25 + h * 5 + w)) * OC3;
#pragma unroll
            for (int o = 0; o < OC3; ++o) acc[o] = fmaf(sv, kp[o], acc[o]);
          }
        }
      }
    }
    long rowbase = (((long)(b * OS + z) * OS + y) * CP8) * (long)OS * 8 + (long)x * 8;
#pragma unroll
    for (int cg = 0; cg < CP8; ++cg) {
      f16x8 pack;
#pragma unroll
      for (int e = 0; e < 8; ++e) {
        int c = cg * 8 + e;
        float v;
        if (c < OC3) v = acc[c];
        else if (c < VEC * 12) {
          int q = c - OC3;
          int cv = q / 9, r9 = q % 9;
          v = acc[cv * 3 + r9 / 3] * acc[cv * 3 + r9 % 3];
        } else v = 0.f;
        pack[e] = (f16)v;
      }
      *(f16x8*)(VT + rowbase + (long)cg * OS * 8) = pack;
    }
  }
}

// ---------------- MFMA conv2 v2: z-tiled wave, input-plane loop ----------------
template <int CP8, int SOUT, int ZT>
__global__ __launch_bounds__(256) void conv2_mfma(const f16* __restrict__ VT,
                                                  const f16* __restrict__ K2,
                                                  float* __restrict__ out,
                                                  int Bc, int IS, int OS, int XG, int ZG) {
  constexpr int KS = CP8 / 4;      // K-steps of 32 channels
  constexpr int CP = CP8 * 8;
  constexpr int NU = ZT + 4;       // input planes touched: zi in [z0-3, z0+ZT]
  int wid = (int)((blockIdx.x * (long)blockDim.x + threadIdx.x) >> 6);
  int lane = threadIdx.x & 63;
  int total = Bc * ZG * OS * XG;
  if (wid >= total) return;
  int xg = wid % XG;
  int y  = (wid / XG) % OS;
  int zg = (wid / (XG * OS)) % ZG;
  int b  = wid / (XG * OS * ZG);
  int z0 = zg * ZT;
  int x0 = xg * 16;
  int lm = lane & 15;   // A row (x offset) / B row (out channel)
  int g  = lane >> 4;   // k-group

  f32x4 acc[ZT];
#pragma unroll
  for (int t = 0; t < ZT; ++t) acc[t] = (f32x4){0.f, 0.f, 0.f, 0.f};

  const f16* bp = K2 + (long)lm * CP + g * 8;

  for (int h = 0; h < 5; ++h) {
    int yi = y - 3 + h;
    if ((unsigned)yi >= (unsigned)IS) continue;
    const f16* base[NU];
    bool zok[NU];
#pragma unroll
    for (int u = 0; u < NU; ++u) {
      int zi = z0 - 3 + u;
      zok[u] = (unsigned)zi < (unsigned)IS;
      int zc = zok[u] ? zi : 0;
      base[u] = VT + (((long)(b * IS + zc) * IS + yi) * CP8) * (long)IS * 8;
    }
#pragma unroll 1
    for (int w = 0; w < 5; ++w) {
      int xi = x0 + lm - 3 + w;
      bool xok = (unsigned)xi < (unsigned)IS;
      const f16* tb = bp + ((long)(h * 5 + w) * 16) * CP;
#pragma unroll
      for (int ks = 0; ks < KS; ++ks) {
        f16x8 bf[5];
#pragma unroll
        for (int d = 0; d < 5; ++d)
          bf[d] = *(const f16x8*)(tb + (long)d * (25 * 16) * CP + ks * 32);
        f16x8 af[NU];
#pragma unroll
        for (int u = 0; u < NU; ++u) {
          af[u] = (f16x8){};
          if (zok[u] && xok)
            af[u] = *(const f16x8*)(base[u] + ((ks * 4 + g) * IS + xi) * 8);
        }
#pragma unroll
        for (int u = 0; u < NU; ++u) {
#pragma unroll
          for (int t = 0; t < ZT; ++t) {
            int d = u - t;                 // compile-time constant per unrolled (u,t)
            if (d >= 0 && d <= 4)
              acc[t] = __builtin_amdgcn_mfma_f32_16x16x32_f16(af[u], bf[d], acc[t], 0, 0, 0);
          }
        }
      }
    }
  }
  // D: col(out ch) = lane&15, row(x) = 4*(lane>>4)+r
  if (lm < SOUT) {
    int oss = OS * OS * OS;
#pragma unroll
    for (int t = 0; t < ZT; ++t) {
      int z = z0 + t;
      if (z < OS) {
        float* op = out + ((long)b * SOUT + lm) * oss + (z * OS + y) * OS;
#pragma unroll
        for (int r = 0; r < 4; ++r) {
          int xm = x0 + g * 4 + r;
          if (xm < OS) op[xm] = acc[t][r];
        }
      }
    }
  }
}

// ---------------- batch-norm reductions (two-stage, deterministic) ----------------
__global__ void stats1(const float* __restrict__ a, float* __restrict__ part,
                       int B, int C, int ss, int nblk) {
  int c = blockIdx.y;
  int tid = threadIdx.x;
  float s = 0.f, s2 = 0.f;
  for (int b = 0; b < B; ++b) {
    const float* ab = a + ((long)b * C + c) * ss;
    for (int p = blockIdx.x * blockDim.x + tid; p < ss; p += nblk * blockDim.x) {
      float x = ab[p];
      s += x;
      s2 += x * x;
    }
  }
  __shared__ float sh[256], sh2[256];
  sh[tid] = s; sh2[tid] = s2;
  __syncthreads();
  for (int off = 128; off > 0; off >>= 1) {
    if (tid < off) { sh[tid] += sh[tid + off]; sh2[tid] += sh2[tid + off]; }
    __syncthreads();
  }
  if (tid == 0) {
    part[(c * nblk + blockIdx.x) * 2 + 0] = sh[0];
    part[(c * nblk + blockIdx.x) * 2 + 1] = sh2[0];
  }
}

__global__ void stats2(const float* __restrict__ part, float* __restrict__ stats,
                       int nblk, float invn) {
  int c = blockIdx.x;
  int tid = threadIdx.x;
  float s = 0.f, s2 = 0.f;
  for (int i = tid; i < nblk; i += blockDim.x) {
    s += part[(c * nblk + i) * 2 + 0];
    s2 += part[(c * nblk + i) * 2 + 1];
  }
  __shared__ float sh[256], sh2[256];
  sh[tid] = s; sh2[tid] = s2;
  __syncthreads();
  for (int off = 128; off > 0; off >>= 1) {
    if (tid < off) { sh[tid] += sh[tid + off]; sh2[tid] += sh2[tid + off]; }
    __syncthreads();
  }
  if (tid == 0) {
    float m = sh[0] * invn;
    float var = sh2[0] * invn - m * m;
    stats[c * 2 + 0] = m;
    stats[c * 2 + 1] = 1.0f / sqrtf(var + EPSF);
  }
}

__global__ void bn_apply(const float* __restrict__ in, float* __restrict__ out,
                         const float* __restrict__ stats, const float* __restrict__ g,
                         const float* __restrict__ be, const float* __restrict__ bias,
                         int C, int ss, int relu) {
  int bc = blockIdx.y;
  int c = bc % C;
  float m = stats[c * 2 + 0];
  float r = stats[c * 2 + 1];
  float ga = g ? g[c] : 1.f;
  float bb = be ? be[c] : 0.f;
  float bi = bias ? bias[c] : 0.f;
  const float* ip = in + (long)bc * ss;
  float* op = out + (long)bc * ss;
  for (int p = blockIdx.x * blockDim.x + threadIdx.x; p < ss; p += gridDim.x * blockDim.x) {
    float xn = (ip[p] - m) * r * ga + bb;
    if (relu) xn = fmaxf(xn + bi, 0.f);
    op[p] = xn;
  }
}

// ---------------- pooling + final batch-norm ----------------
__global__ void pool_k(const float* __restrict__ in, float* __restrict__ pooled, int ss) {
  int bc = blockIdx.x;
  int tid = threadIdx.x;
  const float* p = in + (long)bc * ss;
  float s = 0.f;
  for (int e = tid; e < ss; e += blockDim.x) s += p[e];
  __shared__ float sh[256];
  sh[tid] = s;
  __syncthreads();
  for (int off = 128; off > 0; off >>= 1) {
    if (tid < off) sh[tid] += sh[tid + off];
    __syncthreads();
  }
  if (tid == 0) pooled[bc] = sh[0] / (float)ss;
}

__global__ void final_bn(const float* __restrict__ pooled, const float* __restrict__ g,
                         const float* __restrict__ be, float* __restrict__ out,
                         int B, int C) {
  int tid = threadIdx.x;
  __shared__ float mv[16][2];
  if (tid < C) {
    float s = 0.f, s2 = 0.f;
    for (int b = 0; b < B; ++b) {
      float x = pooled[b * C + tid];
      s += x;
      s2 += x * x;
    }
    float m = s / (float)B;
    float var = s2 / (float)B - m * m;
    mv[tid][0] = m;
    mv[tid][1] = 1.0f / sqrtf(var + EPSF);
  }
  __syncthreads();
  for (int i = tid; i < B * C; i += blockDim.x) {
    int c = i % C;
    out[i] = g[c] * (pooled[i] - mv[c][0]) * mv[c][1] + be[c];
  }
}

// ---------------- host ----------------
extern "C" void kernel_launch(void* const* d_in, const int* in_sizes, int n_in,
                              void* d_out, int out_size, void* d_ws, size_t ws_size,
                              hipStream_t stream) {
  (void)in_sizes; (void)n_in; (void)out_size; (void)ws_size;
  const float* x = (const float*)d_in[0];
  const float* w1[5]; const float* wA[5]; const float* wB[5];
  const float* bias[5]; const float* gam[5]; const float* bet[5];
  for (int i = 0; i < 5; ++i) {
    w1[i]  = (const float*)d_in[1 + i * 6 + 0];
    wA[i]  = (const float*)d_in[1 + i * 6 + 1];
    wB[i]  = (const float*)d_in[1 + i * 6 + 2];
    bias[i]= (const float*)d_in[1 + i * 6 + 3];
    gam[i] = (const float*)d_in[1 + i * 6 + 4];
    bet[i] = (const float*)d_in[1 + i * 6 + 5];
  }
  const float* gamma_out = (const float*)d_in[31];
  const float* beta_out  = (const float*)d_in[32];
  float* out = (float*)d_out;

  // workspace carve — identical to rounds 4-6 (proven fit ~135 MB)
  float* A     = (float*)d_ws;            // 8,388,608
  float* Bb    = A + 8388608;             // 10,976,000
  float* V     = Bb + 10976000;           // 13,799,808 floats (f16 VT = 27.6M f16)
  float* K1    = V + 13799808;            // 96,000
  float* K2    = K1 + 96000;              // 384,000 floats (f16 K2h)
  float* part  = K2 + 384000;             // 8,192
  float* stats = part + 16 * 256 * 2;
  float* pooled= stats + 64;
  f16* VT  = (f16*)V;
  f16* K2h = (f16*)K2;

  const int NB = 256;
  const int Bn = 32;
  const int ZT = 4;

  // --- input batch-norm (C=1, no affine) ---
  {
    int ss = 64 * 64 * 64;
    stats1<<<dim3(NB, 1), 256, 0, stream>>>(x, part, Bn, 1, ss, NB);
    stats2<<<1, 256, 0, stream>>>(part, stats, NB, 1.0f / (float)(Bn * (long)ss));
    int gx = (ss + 255) / 256;
    bn_apply<<<dim3(gx, Bn), 256, 0, stream>>>(x, A, stats, nullptr, nullptr, nullptr, 1, ss, 0);
  }

  const int SINs[5]  = {1, 8, 16, 16, 16};
  const int SOUTs[5] = {8, 16, 16, 16, 10};
  const int VECs[5]  = {4, 12, 16, 16, 13};
  const int ISs[5]   = {64, 35, 21, 14, 10};
  const int VSs[5]   = {33, 19, 12, 8, 6};
  const int OSs[5]   = {35, 21, 14, 10, 8};
  const int CP8s[5]  = {8, 24, 24, 24, 24};   // CP8=20 avoided (never validated; rounds 1-2 failed with it)
  const int CHKs[5]  = {8, 16, 32, 32, 32};

  float* sbuf = A;
  for (int i = 0; i < 5; ++i) {
    float* obuf = (i % 2 == 0) ? Bb : A;
    int IS = ISs[i], VS = VSs[i], OS = OSs[i];
    int VEC = VECs[i], SIN = SINs[i], SOUT = SOUTs[i];

    { int t = SIN * 125 * VEC * 3;
      build_k1<<<(t + 255) / 256, 256, 0, stream>>>(w1[i], K1, VEC, SIN); }

    int CP8 = CP8s[i], CP = CP8 * 8;
    int CHK = CHKs[i];
    int XG = (OS + 15) / 16;
    int ZG = (OS + ZT - 1) / ZT;
    { int t = 125 * 16 * CP;
      build_k2b<<<(t + 255) / 256, 256, 0, stream>>>(wA[i], wB[i], K2h, VEC, SOUT, CP); }
    for (int b0 = 0; b0 < Bn; b0 += CHK) {
      int bc = CHK;
      const float* sp = sbuf + (long)b0 * SIN * IS * IS * IS;
      float* op = obuf + (long)b0 * SOUT * OS * OS * OS;
      int t1 = bc * VS * VS * VS;
      // small grids: 64-thread blocks spread work across more CUs (grid-stride safe)
      int bs1 = (t1 < 256 * 256) ? 64 : 256;
      int g1 = (t1 + bs1 - 1) / bs1;
      long waves = (long)bc * ZG * OS * XG;
      int g2 = (int)((waves * 64 + 255) / 256);
      switch (i) {
        case 0:
          conv1_vt<1, 4, 8><<<g1, bs1, 0, stream>>>(sp, K1, VT, bc, IS, VS);
          conv2_mfma<8, 8, ZT><<<g2, 256, 0, stream>>>(VT, K2h, op, bc, VS, OS, XG, ZG);
          break;
        case 1:
          conv1_vt<8, 12, 24><<<g1, bs1, 0, stream>>>(sp, K1, VT, bc, IS, VS);
          conv2_mfma<24, 16, ZT><<<g2, 256, 0, stream>>>(VT, K2h, op, bc, VS, OS, XG, ZG);
          break;
        case 2:
          conv1_vt<16, 16, 24><<<g1, bs1, 0, stream>>>(sp, K1, VT, bc, IS, VS);
          conv2_mfma<24, 16, ZT><<<g2, 256, 0, stream>>>(VT, K2h, op, bc, VS, OS, XG, ZG);
          break;
        case 3:
          conv1_vt<16, 16, 24><<<g1, bs1, 0, stream>>>(sp, K1, VT, bc, IS, VS);
          conv2_mfma<24, 16, ZT><<<g2, 256, 0, stream>>>(VT, K2h, op, bc, VS, OS, XG, ZG);
          break;
        case 4:
          conv1_vt<16, 13, 24><<<g1, bs1, 0, stream>>>(sp, K1, VT, bc, IS, VS);
          conv2_mfma<24, 10, ZT><<<g2, 256, 0, stream>>>(VT, K2h, op, bc, VS, OS, XG, ZG);
          break;
      }
    }

    { int ss = OS * OS * OS;
      stats1<<<dim3(NB, SOUT), 256, 0, stream>>>(obuf, part, Bn, SOUT, ss, NB);
      stats2<<<SOUT, 256, 0, stream>>>(part, stats, NB, 1.0f / (float)((long)Bn * ss));
      int gx = (ss + 255) / 256;
      bn_apply<<<dim3(gx, Bn * SOUT), 256, 0, stream>>>(obuf, obuf, stats, gam[i], bet[i],
                                                        bias[i], SOUT, ss, (i < 4) ? 1 : 0);
    }
    sbuf = obuf;
  }

  pool_k<<<Bn * 10, 256, 0, stream>>>(sbuf, pooled, 8 * 8 * 8);
  final_bn<<<1, 64, 0, stream>>>(pooled, gamma_out, beta_out, out, Bn, 10);
}